// Round 1
// baseline (3488.820 us; speedup 1.0000x reference)
//
#include <hip/hip_runtime.h>
#include <hip/hip_cooperative_groups.h>

namespace cg = cooperative_groups;

typedef __bf16 bf16;
typedef __bf16 bf16x8 __attribute__((ext_vector_type(8)));
typedef __bf16 bf16x4 __attribute__((ext_vector_type(4)));
typedef float f32x4 __attribute__((ext_vector_type(4)));

#define GLL16(gp, lp) __builtin_amdgcn_global_load_lds( \
    (__attribute__((address_space(1))) void*)(gp), \
    (__attribute__((address_space(3))) void*)(lp), 16, 0, 0)

// ---------------- fused weight conversion (all 5 weight mats -> contiguous bf16) ----
__global__ void cvt_all_kernel(const float* __restrict__ a, const float* __restrict__ b,
                               const float* __restrict__ c, const float* __restrict__ d,
                               const float* __restrict__ e, bf16* __restrict__ dst) {
    int i = blockIdx.x * 256 + threadIdx.x;
    float v;
    if      (i < 2097152) v = a[i];
    else if (i < 2228224) v = b[i - 2097152];
    else if (i < 3014656) v = c[i - 2228224];
    else if (i < 3801088) v = d[i - 3014656];
    else if (i < 4325376) v = e[i - 3801088];
    else return;
    dst[i] = (bf16)v;
}

// ---------------- conv1 split-K: x fp32 [26624,8192] @ w1^T [256,8192] -> fp32 partials
// grid (416, 4): 64-row tile x full N=256, K-slice 2048 per block -> 6.5 blocks/CU
__global__ __launch_bounds__(256) void conv1_kernel(
    const float* __restrict__ A, const bf16* __restrict__ B, float* __restrict__ P)
{
    const int K = 8192;
    __shared__ __align__(16) bf16 As[64 * 32];
    __shared__ __align__(16) bf16 Bs[256 * 32];
    const int tid = threadIdx.x;
    const int wave = tid >> 6, lane = tid & 63;
    const int quad = lane >> 4, l16 = lane & 15;
    const int wm = (wave & 1) * 32, wn = (wave >> 1) * 128;
    const int m0 = blockIdx.x * 64;
    const int k0 = blockIdx.y * 2048;
    const int ar = tid >> 2, akq = tid & 3;

    f32x4 acc[2][8] = {};
    const float* agp = A + (size_t)(m0 + ar) * K + akq * 8;

    for (int kt = k0; kt < k0 + 2048; kt += 32) {
        const float4* ap = (const float4*)(agp + kt);
        float4 p0 = ap[0], p1 = ap[1];
        bf16x8 v;
        v[0]=(bf16)p0.x; v[1]=(bf16)p0.y; v[2]=(bf16)p0.z; v[3]=(bf16)p0.w;
        v[4]=(bf16)p1.x; v[5]=(bf16)p1.y; v[6]=(bf16)p1.z; v[7]=(bf16)p1.w;
        *(bf16x8*)(As + tid * 8) = v;
        #pragma unroll
        for (int s = 0; s < 4; ++s) {
            int c = tid + s * 256;
            GLL16(B + (size_t)(c >> 2) * K + kt + (c & 3) * 8, Bs + c * 8);
        }
        __syncthreads();
        bf16x8 af[2], bfr[8];
        #pragma unroll
        for (int i = 0; i < 2; ++i)
            af[i] = *(const bf16x8*)(As + (wm + i * 16 + l16) * 32 + quad * 8);
        #pragma unroll
        for (int j = 0; j < 8; ++j)
            bfr[j] = *(const bf16x8*)(Bs + (wn + j * 16 + l16) * 32 + quad * 8);
        #pragma unroll
        for (int i = 0; i < 2; ++i)
            #pragma unroll
            for (int j = 0; j < 8; ++j)
                acc[i][j] = __builtin_amdgcn_mfma_f32_16x16x32_bf16(af[i], bfr[j], acc[i][j], 0, 0, 0);
        __syncthreads();
    }
    float* Pp = P + (size_t)blockIdx.y * 26624 * 256;
    #pragma unroll
    for (int i = 0; i < 2; ++i)
        #pragma unroll
        for (int j = 0; j < 8; ++j)
            #pragma unroll
            for (int r = 0; r < 4; ++r) {
                int row = m0 + wm + i * 16 + quad * 4 + r;
                int col = wn + j * 16 + l16;
                Pp[(size_t)row * 256 + col] = acc[i][j][r];
            }
}

// reduce 4 partial planes + bias + threshold -> bf16 h1
__global__ void conv1_reduce_kernel(const float* __restrict__ P, const float* __restrict__ bias,
                                    bf16* __restrict__ out) {
    const size_t plane = 26624ull * 256 / 4;   // float4 units
    size_t i = blockIdx.x * 256 + threadIdx.x; // 0 .. 1703935
    const float4* p = (const float4*)P;
    float4 s0 = p[i], s1 = p[i + plane], s2 = p[i + 2 * plane], s3 = p[i + 3 * plane];
    int col = (int)((i * 4) & 255);
    float4 bb = *(const float4*)(bias + col);
    float r0 = s0.x + s1.x + s2.x + s3.x + bb.x;
    float r1 = s0.y + s1.y + s2.y + s3.y + bb.y;
    float r2 = s0.z + s1.z + s2.z + s3.z + bb.z;
    float r3 = s0.w + s1.w + s2.w + s3.w + bb.w;
    bf16x4 o;
    o[0] = (bf16)(r0 > 1e-6f ? r0 : 0.0f);
    o[1] = (bf16)(r1 > 1e-6f ? r1 : 0.0f);
    o[2] = (bf16)(r2 > 1e-6f ? r2 : 0.0f);
    o[3] = (bf16)(r3 > 1e-6f ? r3 : 0.0f);
    *(bf16x4*)(out + i * 4) = o;
}

// ---------------- generic 128x128 bf16 GEMM: C = A[M,K] @ B[N,K]^T + bias
// mode 0: bias + threshold, bf16 out (conv2) | mode 1: bias, bf16 out (gi) | mode 2: bias, fp32 out
__global__ __launch_bounds__(256) void gemm128_kernel(
    const bf16* __restrict__ A, const bf16* __restrict__ B,
    const float* __restrict__ bias, bf16* __restrict__ outh,
    float* __restrict__ outf, int M, int N, int K, int mode)
{
    __shared__ __align__(16) bf16 As[128 * 32];
    __shared__ __align__(16) bf16 Bs[128 * 32];
    const int tid = threadIdx.x;
    const int wave = tid >> 6, lane = tid & 63;
    const int quad = lane >> 4, l16 = lane & 15;
    const int wm = (wave & 1) * 64, wn = (wave >> 1) * 64;
    const int m0 = blockIdx.y * 128, n0 = blockIdx.x * 128;
    const int ar = tid >> 2, akq = tid & 3;

    f32x4 acc[4][4] = {};

    for (int kt = 0; kt < K; kt += 32) {
        GLL16(A + (size_t)(m0 + ar) * K + kt + akq * 8, As + tid * 8);
        GLL16(A + (size_t)(m0 + 64 + ar) * K + kt + akq * 8, As + 2048 + tid * 8);
        GLL16(B + (size_t)(n0 + ar) * K + kt + akq * 8, Bs + tid * 8);
        GLL16(B + (size_t)(n0 + 64 + ar) * K + kt + akq * 8, Bs + 2048 + tid * 8);
        __syncthreads();
        bf16x8 af[4], bfr[4];
        #pragma unroll
        for (int i = 0; i < 4; ++i) {
            af[i]  = *(const bf16x8*)(As + (wm + i * 16 + l16) * 32 + quad * 8);
            bfr[i] = *(const bf16x8*)(Bs + (wn + i * 16 + l16) * 32 + quad * 8);
        }
        #pragma unroll
        for (int i = 0; i < 4; ++i)
            #pragma unroll
            for (int j = 0; j < 4; ++j)
                acc[i][j] = __builtin_amdgcn_mfma_f32_16x16x32_bf16(af[i], bfr[j], acc[i][j], 0, 0, 0);
        __syncthreads();
    }
    #pragma unroll
    for (int i = 0; i < 4; ++i)
        #pragma unroll
        for (int j = 0; j < 4; ++j)
            #pragma unroll
            for (int r = 0; r < 4; ++r) {
                int row = m0 + wm + i * 16 + quad * 4 + r;
                int col = n0 + wn + j * 16 + l16;
                float v = acc[i][j][r] + bias[col];
                if (mode == 0) v = (v > 1e-6f) ? v : 0.0f;
                if (mode == 2) outf[(size_t)row * N + col] = v;
                else outh[(size_t)row * N + col] = (bf16)v;
            }
}

// ---------------- persistent GRU: all 26 steps in ONE cooperative kernel.
// grid 256 blocks (16 nb x 16 mb) = 1 block/CU (LDS-forced). whh tile resident in LDS
// across all steps; grid.sync() + agent fences between steps (cross-XCD L2 non-coherent).
__global__ __launch_bounds__(256) void gru_persistent_kernel(
    const bf16* __restrict__ gi,    // [26624,1536] planar cols (r|z|n planes of 512)
    const bf16* __restrict__ whh,   // [1536,512] original layout
    const float* __restrict__ bhh,  // [1536]
    bf16* __restrict__ H0,          // [1024,512] ping (final h lands here: t=25 odd)
    bf16* __restrict__ H1)          // [1024,512] pong
{
    __shared__ __align__(16) bf16 ws[96 * 520];     // 99840 B: whh tile, resident all 26 steps
    __shared__ __align__(16) float ghs[64 * 100];   // 25600 B: gh staging per step
    const int tid = threadIdx.x;
    const int wave = tid >> 6, lane = tid & 63;
    const int quad = lane >> 4, l16 = lane & 15;
    const int wm = (wave & 1) * 32, wn = (wave >> 1) * 48;
    const int nb = blockIdx.x & 15, mb = blockIdx.x >> 4;
    const int m0 = mb * 64;
    cg::grid_group grid = cg::this_grid();

    // stage whh rows {d, 512+d, 1024+d : d in [nb*32, nb*32+32)} -> 96 x (512 pad 520), ONCE
    #pragma unroll
    for (int ii = 0; ii < 24; ++ii) {
        int cc = ii * 256 + tid;        // 16B chunk id, 64 chunks/row
        int row = cc >> 6;
        int col = (cc & 63) * 8;
        int gr = (row < 32) ? nb * 32 + row
               : (row < 64) ? 512 + nb * 32 + (row - 32)
                            : 1024 + nb * 32 + (row - 64);
        *(bf16x8*)(ws + row * 520 + col) = *(const bf16x8*)(whh + (size_t)gr * 512 + col);
    }

    // per-thread gate column is loop-invariant: (it*256+tid)&31 == tid&31
    const int ldg = tid & 31;
    const int dgf = nb * 32 + ldg;
    const float bR = bhh[dgf], bZ = bhh[512 + dgf], bN = bhh[1024 + dgf];

    for (int t = 0; t < 26; ++t) {
        const bf16* __restrict__ hprev = (t & 1) ? H1 : H0;
        bf16* __restrict__ hout = (t & 1) ? H0 : H1;

        if (t > 0) {
            // gh = hprev @ whh^T for this (mb, nb) tile: 64 rows x 96 gate-cols
            f32x4 acc[2][3] = {};
            #pragma unroll
            for (int kt = 0; kt < 512; kt += 32) {
                bf16x8 af[2], bfr[3];
                #pragma unroll
                for (int i = 0; i < 2; ++i)
                    af[i] = *(const bf16x8*)(hprev + (size_t)(m0 + wm + i * 16 + l16) * 512 + kt + quad * 8);
                #pragma unroll
                for (int j = 0; j < 3; ++j)
                    bfr[j] = *(const bf16x8*)(ws + (wn + j * 16 + l16) * 520 + kt + quad * 8);
                #pragma unroll
                for (int i = 0; i < 2; ++i)
                    #pragma unroll
                    for (int j = 0; j < 3; ++j)
                        acc[i][j] = __builtin_amdgcn_mfma_f32_16x16x32_bf16(af[i], bfr[j], acc[i][j], 0, 0, 0);
            }
            #pragma unroll
            for (int i = 0; i < 2; ++i)
                #pragma unroll
                for (int j = 0; j < 3; ++j)
                    #pragma unroll
                    for (int r = 0; r < 4; ++r) {
                        int lrow = wm + i * 16 + quad * 4 + r;
                        int lcol = wn + j * 16 + l16;          // 0..95: plane = lcol/32
                        int plane = lcol >> 5, dl = lcol & 31;
                        ghs[lrow * 100 + lcol] = acc[i][j][r] + bhh[plane * 512 + nb * 32 + dl];
                    }
            __syncthreads();
        }

        // gates: 64 rows x 32 d per block
        #pragma unroll
        for (int it = 0; it < 8; ++it) {
            int lrow = it * 8 + (tid >> 5);
            int b = m0 + lrow;
            float ghr, ghz, ghn, hp;
            if (t == 0) { ghr = bR; ghz = bZ; ghn = bN; hp = 0.0f; }
            else {
                ghr = ghs[lrow * 100 + ldg];
                ghz = ghs[lrow * 100 + 32 + ldg];
                ghn = ghs[lrow * 100 + 64 + ldg];
                hp  = (float)hprev[(size_t)b * 512 + dgf];
            }
            size_t gb = ((size_t)b * 26 + t) * 1536;
            float gir = (float)gi[gb + dgf], giz = (float)gi[gb + 512 + dgf], gin = (float)gi[gb + 1024 + dgf];
            float rr = 1.0f / (1.0f + __expf(-(gir + ghr)));
            float zz = 1.0f / (1.0f + __expf(-(giz + ghz)));
            float xx = gin + rr * ghn;
            float nn = 1.0f - 2.0f / (__expf(2.0f * xx) + 1.0f);   // tanh
            hout[(size_t)b * 512 + dgf] = (bf16)((1.0f - zz) * nn + zz * hp);
        }

        // release our hout stores to agent scope, barrier, then invalidate stale
        // L1/L2 lines before re-reading the ping-pong buffer next step.
        __threadfence();
        grid.sync();
        __threadfence();
    }
}

extern "C" void kernel_launch(void* const* d_in, const int* in_sizes, int n_in,
                              void* d_out, int out_size, void* d_ws, size_t ws_size,
                              hipStream_t stream) {
    const float* x       = (const float*)d_in[0];
    const float* conv1_w = (const float*)d_in[1];
    const float* conv1_b = (const float*)d_in[2];
    const float* conv2_w = (const float*)d_in[3];
    const float* conv2_b = (const float*)d_in[4];
    const float* w_ih    = (const float*)d_in[5];
    const float* w_hh    = (const float*)d_in[6];
    const float* b_ih    = (const float*)d_in[7];
    const float* b_hh    = (const float*)d_in[8];
    const float* lin_w   = (const float*)d_in[9];
    const float* lin_b   = (const float*)d_in[10];
    float* out = (float*)d_out;

    // workspace: fp32 partials first (16B aligned), then bf16 region
    float* P   = (float*)d_ws;              // 4 * 26624*256 fp32 = 109 MB
    bf16* wsb  = (bf16*)(P + 4ull * 26624 * 256);
    bf16* w1   = wsb;                 // 2097152
    bf16* w2   = w1  + 2097152;       // 131072
    bf16* wih  = w2  + 131072;        // 786432
    bf16* whh  = wih + 786432;        // 786432
    bf16* wlin = whh + 786432;        // 524288
    bf16* h1   = wlin + 524288;       // 6815744
    bf16* h2   = h1  + 6815744;       // 13631488
    bf16* gib  = h2  + 13631488;      // 40894464
    bf16* H0   = gib + 40894464;      // 524288
    bf16* H1   = H0  + 524288;        // 524288

    cvt_all_kernel<<<16896, 256, 0, stream>>>(conv1_w, conv2_w, w_ih, w_hh, lin_w, w1);

    // conv1 split-K=4 + reduce
    conv1_kernel<<<dim3(416, 4), 256, 0, stream>>>(x, w1, P);
    conv1_reduce_kernel<<<6656, 256, 0, stream>>>(P, conv1_b, h1);
    // conv2: [26624,256] -> [26624,512]
    gemm128_kernel<<<dim3(4, 208), 256, 0, stream>>>(h1, w2, conv2_b, h2, nullptr, 26624, 512, 256, 0);
    // gi = h2 @ w_ih^T + b_ih (planar): [26624,1536]
    gemm128_kernel<<<dim3(12, 208), 256, 0, stream>>>(h2, wih, b_ih, gib, nullptr, 26624, 1536, 512, 1);
    // all 26 GRU steps in one persistent cooperative kernel (256 blocks = 1/CU)
    {
        const bf16* a0 = gib; const bf16* a1 = whh; const float* a2 = b_hh;
        bf16* a3 = H0; bf16* a4 = H1;
        void* args[] = { &a0, &a1, &a2, &a3, &a4 };
        hipLaunchCooperativeKernel((void*)gru_persistent_kernel, dim3(256), dim3(256), args, 0, stream);
    }
    // final: H0 [1024,512] @ lin_w^T + b -> out fp32 [1024,1024]
    gemm128_kernel<<<dim3(8, 8), 256, 0, stream>>>(H0, wlin, lin_b, nullptr, out, 1024, 1024, 512, 2);
}

// Round 3
// 1822.560 us; speedup vs baseline: 1.9142x; 1.9142x over previous
//
#include <hip/hip_runtime.h>

typedef __bf16 bf16;
typedef __bf16 bf16x8 __attribute__((ext_vector_type(8)));
typedef __bf16 bf16x4 __attribute__((ext_vector_type(4)));
typedef float f32x4 __attribute__((ext_vector_type(4)));

#define GLL16(gp, lp) __builtin_amdgcn_global_load_lds( \
    (__attribute__((address_space(1))) void*)(gp), \
    (__attribute__((address_space(3))) void*)(lp), 16, 0, 0)

// ---------------- fused weight conversion (all 5 weight mats -> contiguous bf16) ----
__global__ void cvt_all_kernel(const float* __restrict__ a, const float* __restrict__ b,
                               const float* __restrict__ c, const float* __restrict__ d,
                               const float* __restrict__ e, bf16* __restrict__ dst) {
    int i = blockIdx.x * 256 + threadIdx.x;
    float v;
    if      (i < 2097152) v = a[i];
    else if (i < 2228224) v = b[i - 2097152];
    else if (i < 3014656) v = c[i - 2228224];
    else if (i < 3801088) v = d[i - 3014656];
    else if (i < 4325376) v = e[i - 3801088];
    else return;
    dst[i] = (bf16)v;
}

// ---------------- conv1 single-pass: x fp32 [26624,8192] @ w1^T [256,8192] -> h1 bf16
// grid 208: 128-row tile x full N=256, full K per block. Fused bias + threshold.
// (round 2: replaces split-K=4 + reduce — saves 218 MB partial traffic + one launch;
//  208/256 CUs busy = same 81% utilization as the old 416-block 2-wave schedule)
__global__ __launch_bounds__(256) void conv1_kernel(
    const float* __restrict__ A, const bf16* __restrict__ B,
    const float* __restrict__ bias, bf16* __restrict__ out)
{
    const int K = 8192;
    __shared__ __align__(16) bf16 As[128 * 32];
    __shared__ __align__(16) bf16 Bs[256 * 32];
    const int tid = threadIdx.x;
    const int wave = tid >> 6, lane = tid & 63;
    const int quad = lane >> 4, l16 = lane & 15;
    const int wm = (wave & 1) * 64, wn = (wave >> 1) * 128;
    const int m0 = blockIdx.x * 128;
    const int ar2 = tid >> 1;             // row 0..127
    const int ak16 = (tid & 1) * 16;      // k-offset 0 or 16

    f32x4 acc[4][8] = {};
    const float* agp = A + (size_t)(m0 + ar2) * K + ak16;

    for (int kt = 0; kt < K; kt += 32) {
        // stage A: 128 rows x 32 k (fp32 -> bf16), 16 floats/thread
        const float4* ap = (const float4*)(agp + kt);
        float4 p0 = ap[0], p1 = ap[1], p2 = ap[2], p3 = ap[3];
        bf16x8 v0, v1;
        v0[0]=(bf16)p0.x; v0[1]=(bf16)p0.y; v0[2]=(bf16)p0.z; v0[3]=(bf16)p0.w;
        v0[4]=(bf16)p1.x; v0[5]=(bf16)p1.y; v0[6]=(bf16)p1.z; v0[7]=(bf16)p1.w;
        v1[0]=(bf16)p2.x; v1[1]=(bf16)p2.y; v1[2]=(bf16)p2.z; v1[3]=(bf16)p2.w;
        v1[4]=(bf16)p3.x; v1[5]=(bf16)p3.y; v1[6]=(bf16)p3.z; v1[7]=(bf16)p3.w;
        *(bf16x8*)(As + ar2 * 32 + ak16) = v0;
        *(bf16x8*)(As + ar2 * 32 + ak16 + 8) = v1;
        // stage B: 256 rows x 32 k via global_load_lds (16B x 4/thread)
        #pragma unroll
        for (int s = 0; s < 4; ++s) {
            int c = tid + s * 256;
            GLL16(B + (size_t)(c >> 2) * K + kt + (c & 3) * 8, Bs + c * 8);
        }
        __syncthreads();
        bf16x8 af[4], bfr[8];
        #pragma unroll
        for (int i = 0; i < 4; ++i)
            af[i] = *(const bf16x8*)(As + (wm + i * 16 + l16) * 32 + quad * 8);
        #pragma unroll
        for (int j = 0; j < 8; ++j)
            bfr[j] = *(const bf16x8*)(Bs + (wn + j * 16 + l16) * 32 + quad * 8);
        #pragma unroll
        for (int i = 0; i < 4; ++i)
            #pragma unroll
            for (int j = 0; j < 8; ++j)
                acc[i][j] = __builtin_amdgcn_mfma_f32_16x16x32_bf16(af[i], bfr[j], acc[i][j], 0, 0, 0);
        __syncthreads();
    }
    #pragma unroll
    for (int i = 0; i < 4; ++i)
        #pragma unroll
        for (int j = 0; j < 8; ++j)
            #pragma unroll
            for (int r = 0; r < 4; ++r) {
                int row = m0 + wm + i * 16 + quad * 4 + r;
                int col = wn + j * 16 + l16;
                float v = acc[i][j][r] + bias[col];
                v = (v > 1e-6f) ? v : 0.0f;
                out[(size_t)row * 256 + col] = (bf16)v;
            }
}

// ---------------- generic 128x128 bf16 GEMM: C = A[M,K] @ B[N,K]^T + bias
// mode 0: bias + threshold, bf16 out (conv2) | mode 1: bias, bf16 out (gi) | mode 2: bias, fp32 out
__global__ __launch_bounds__(256) void gemm128_kernel(
    const bf16* __restrict__ A, const bf16* __restrict__ B,
    const float* __restrict__ bias, bf16* __restrict__ outh,
    float* __restrict__ outf, int M, int N, int K, int mode)
{
    __shared__ __align__(16) bf16 As[128 * 32];
    __shared__ __align__(16) bf16 Bs[128 * 32];
    const int tid = threadIdx.x;
    const int wave = tid >> 6, lane = tid & 63;
    const int quad = lane >> 4, l16 = lane & 15;
    const int wm = (wave & 1) * 64, wn = (wave >> 1) * 64;
    const int m0 = blockIdx.y * 128, n0 = blockIdx.x * 128;
    const int ar = tid >> 2, akq = tid & 3;

    f32x4 acc[4][4] = {};

    for (int kt = 0; kt < K; kt += 32) {
        GLL16(A + (size_t)(m0 + ar) * K + kt + akq * 8, As + tid * 8);
        GLL16(A + (size_t)(m0 + 64 + ar) * K + kt + akq * 8, As + 2048 + tid * 8);
        GLL16(B + (size_t)(n0 + ar) * K + kt + akq * 8, Bs + tid * 8);
        GLL16(B + (size_t)(n0 + 64 + ar) * K + kt + akq * 8, Bs + 2048 + tid * 8);
        __syncthreads();
        bf16x8 af[4], bfr[4];
        #pragma unroll
        for (int i = 0; i < 4; ++i) {
            af[i]  = *(const bf16x8*)(As + (wm + i * 16 + l16) * 32 + quad * 8);
            bfr[i] = *(const bf16x8*)(Bs + (wn + i * 16 + l16) * 32 + quad * 8);
        }
        #pragma unroll
        for (int i = 0; i < 4; ++i)
            #pragma unroll
            for (int j = 0; j < 4; ++j)
                acc[i][j] = __builtin_amdgcn_mfma_f32_16x16x32_bf16(af[i], bfr[j], acc[i][j], 0, 0, 0);
        __syncthreads();
    }
    #pragma unroll
    for (int i = 0; i < 4; ++i)
        #pragma unroll
        for (int j = 0; j < 4; ++j)
            #pragma unroll
            for (int r = 0; r < 4; ++r) {
                int row = m0 + wm + i * 16 + quad * 4 + r;
                int col = n0 + wn + j * 16 + l16;
                float v = acc[i][j][r] + bias[col];
                if (mode == 0) v = (v > 1e-6f) ? v : 0.0f;
                if (mode == 2) outf[(size_t)row * N + col] = v;
                else outh[(size_t)row * N + col] = (bf16)v;
            }
}

// ---------------- GRU step: whh tile resident in LDS (padded), barrier-free K-loop,
// planar gi/whh (no interleave). grid (16 nb, 16 mb), 256 thr.
// NOTE (round 1): persistent+grid.sync variant measured 80 us/step (L2 wb/inv per fence,
// cross-XCD); per-step launches are ~7x cheaper. Keep launches.
__global__ __launch_bounds__(256) void gru_step_kernel(
    const bf16* __restrict__ gi,    // [26624,1536] planar cols (r|z|n planes of 512)
    const bf16* __restrict__ whh,   // [1536,512] original layout
    const float* __restrict__ bhh,  // [1536]
    const bf16* __restrict__ hprev, // [1024,512]
    bf16* __restrict__ hout,        // [1024,512]
    int t, int first)
{
    __shared__ __align__(16) char smem[99840];   // whhS 96x520 bf16 | reused as ghs 64x100 f32
    const int tid = threadIdx.x;
    const int wave = tid >> 6, lane = tid & 63;
    const int quad = lane >> 4, l16 = lane & 15;
    const int wm = (wave & 1) * 32, wn = (wave >> 1) * 48;
    const int nb = blockIdx.x, mb = blockIdx.y;
    const int m0 = mb * 64;
    float* ghs = (float*)smem;

    if (!first) {
        bf16* ws = (bf16*)smem;
        // stage whh rows {d, 512+d, 1024+d : d in [nb*32, nb*32+32)} -> 96 x (512 pad 520)
        bf16x8 tmp[24];
        #pragma unroll
        for (int ii = 0; ii < 24; ++ii) {
            int cc = ii * 256 + tid;        // 16B chunk id, 64 chunks/row
            int row = cc >> 6;
            int col = (cc & 63) * 8;
            int gr = (row < 32) ? nb * 32 + row
                   : (row < 64) ? 512 + nb * 32 + (row - 32)
                                : 1024 + nb * 32 + (row - 64);
            tmp[ii] = *(const bf16x8*)(whh + (size_t)gr * 512 + col);
        }
        #pragma unroll
        for (int ii = 0; ii < 24; ++ii) {
            int cc = ii * 256 + tid;
            int row = cc >> 6;
            int col = (cc & 63) * 8;
            *(bf16x8*)(ws + row * 520 + col) = tmp[ii];
        }
        __syncthreads();

        f32x4 acc[2][3] = {};
        #pragma unroll
        for (int kt = 0; kt < 512; kt += 32) {
            bf16x8 af[2], bfr[3];
            #pragma unroll
            for (int i = 0; i < 2; ++i)
                af[i] = *(const bf16x8*)(hprev + (size_t)(m0 + wm + i * 16 + l16) * 512 + kt + quad * 8);
            #pragma unroll
            for (int j = 0; j < 3; ++j)
                bfr[j] = *(const bf16x8*)(ws + (wn + j * 16 + l16) * 520 + kt + quad * 8);
            #pragma unroll
            for (int i = 0; i < 2; ++i)
                #pragma unroll
                for (int j = 0; j < 3; ++j)
                    acc[i][j] = __builtin_amdgcn_mfma_f32_16x16x32_bf16(af[i], bfr[j], acc[i][j], 0, 0, 0);
        }
        __syncthreads();   // whhS dead; reuse as ghs
        #pragma unroll
        for (int i = 0; i < 2; ++i)
            #pragma unroll
            for (int j = 0; j < 3; ++j)
                #pragma unroll
                for (int r = 0; r < 4; ++r) {
                    int lrow = wm + i * 16 + quad * 4 + r;
                    int lcol = wn + j * 16 + l16;          // 0..95: plane = lcol/32
                    int plane = lcol >> 5, dl = lcol & 31;
                    ghs[lrow * 100 + lcol] = acc[i][j][r] + bhh[plane * 512 + nb * 32 + dl];
                }
        __syncthreads();
    }

    // gates: 64 rows x 32 d per block
    #pragma unroll
    for (int it = 0; it < 8; ++it) {
        int item = it * 256 + tid;
        int lrow = item >> 5, ld = item & 31;
        int b = m0 + lrow;
        int dg = nb * 32 + ld;
        float ghr, ghz, ghn, hp;
        if (first) { ghr = bhh[dg]; ghz = bhh[512 + dg]; ghn = bhh[1024 + dg]; hp = 0.0f; }
        else {
            ghr = ghs[lrow * 100 + ld];
            ghz = ghs[lrow * 100 + 32 + ld];
            ghn = ghs[lrow * 100 + 64 + ld];
            hp  = (float)hprev[(size_t)b * 512 + dg];
        }
        size_t gb = ((size_t)b * 26 + t) * 1536;
        float gir = (float)gi[gb + dg], giz = (float)gi[gb + 512 + dg], gin = (float)gi[gb + 1024 + dg];
        float rr = 1.0f / (1.0f + __expf(-(gir + ghr)));
        float zz = 1.0f / (1.0f + __expf(-(giz + ghz)));
        float xx = gin + rr * ghn;
        float nn = 1.0f - 2.0f / (__expf(2.0f * xx) + 1.0f);   // tanh
        hout[(size_t)b * 512 + dg] = (bf16)((1.0f - zz) * nn + zz * hp);
    }
}

extern "C" void kernel_launch(void* const* d_in, const int* in_sizes, int n_in,
                              void* d_out, int out_size, void* d_ws, size_t ws_size,
                              hipStream_t stream) {
    const float* x       = (const float*)d_in[0];
    const float* conv1_w = (const float*)d_in[1];
    const float* conv1_b = (const float*)d_in[2];
    const float* conv2_w = (const float*)d_in[3];
    const float* conv2_b = (const float*)d_in[4];
    const float* w_ih    = (const float*)d_in[5];
    const float* w_hh    = (const float*)d_in[6];
    const float* b_ih    = (const float*)d_in[7];
    const float* b_hh    = (const float*)d_in[8];
    const float* lin_w   = (const float*)d_in[9];
    const float* lin_b   = (const float*)d_in[10];
    float* out = (float*)d_out;

    // workspace layout kept identical to the split-K version (P region now unused)
    float* P   = (float*)d_ws;              // 4 * 26624*256 fp32 = 109 MB (unused)
    bf16* wsb  = (bf16*)(P + 4ull * 26624 * 256);
    bf16* w1   = wsb;                 // 2097152
    bf16* w2   = w1  + 2097152;       // 131072
    bf16* wih  = w2  + 131072;        // 786432
    bf16* whh  = wih + 786432;        // 786432
    bf16* wlin = whh + 786432;        // 524288
    bf16* h1   = wlin + 524288;       // 6815744
    bf16* h2   = h1  + 6815744;       // 13631488
    bf16* gib  = h2  + 13631488;      // 40894464
    bf16* H0   = gib + 40894464;      // 524288
    bf16* H1   = H0  + 524288;        // 524288

    cvt_all_kernel<<<16896, 256, 0, stream>>>(conv1_w, conv2_w, w_ih, w_hh, lin_w, w1);

    // conv1 single-pass, fused bias+threshold: [26624,8192] -> [26624,256]
    conv1_kernel<<<208, 256, 0, stream>>>(x, w1, conv1_b, h1);
    // conv2: [26624,256] -> [26624,512]
    gemm128_kernel<<<dim3(4, 208), 256, 0, stream>>>(h1, w2, conv2_b, h2, nullptr, 26624, 512, 256, 0);
    // gi = h2 @ w_ih^T + b_ih (planar): [26624,1536]
    gemm128_kernel<<<dim3(12, 208), 256, 0, stream>>>(h2, wih, b_ih, gib, nullptr, 26624, 1536, 512, 1);
    // 26 GRU steps, ping-pong
    for (int t = 0; t < 26; ++t) {
        const bf16* hp = (t & 1) ? H1 : H0;
        bf16* ho = (t & 1) ? H0 : H1;
        gru_step_kernel<<<dim3(16, 16), 256, 0, stream>>>(gib, whh, b_hh, hp, ho, t, t == 0);
    }
    // final: H0 [1024,512] @ lin_w^T + b -> out fp32 [1024,1024]
    gemm128_kernel<<<dim3(8, 8), 256, 0, stream>>>(H0, wlin, lin_b, nullptr, out, 1024, 1024, 512, 2);
}